// Round 1
// baseline (2382.532 us; speedup 1.0000x reference)
//
#include <hip/hip_runtime.h>
#include <math.h>

// ---------------- problem constants ----------------
#define BBATCH 4096
#define LLEN   4096
#define DDIM   1024
#define CCLS   64
#define NSUP   8192
#define NTOT   12288            // NSUP + BBATCH
#define FEPS   1e-12f

// scalar accumulator slots
#define SC_SUMP  0
#define SC_SUME  1
#define SC_SUMWC 2
#define SC_TSAL  3
#define SC_L2NUM 4
#define SC_L3NUM 5

// ---------------- workspace layout (float offsets) ----------------
static const size_t OFF_FEATS  = 0;                                   // B*D
static const size_t OFF_PROBS  = OFF_FEATS  + (size_t)BBATCH*DDIM;    // B*C
static const size_t OFF_LOGP   = OFF_PROBS  + (size_t)BBATCH*CCLS;    // B*C
static const size_t OFF_FNORM  = OFF_LOGP   + (size_t)BBATCH*CCLS;    // B
static const size_t OFF_SNORM  = OFF_FNORM  + BBATCH;                 // N
static const size_t OFF_PMAX   = OFF_SNORM  + NSUP;                   // B
static const size_t OFF_EROW   = OFF_PMAX   + BBATCH;                 // B
static const size_t OFF_WC     = OFF_EROW   + BBATCH;                 // B
static const size_t OFF_PRED   = OFF_WC     + BBATCH;                 // B (int)
static const size_t OFF_RB     = OFF_PRED   + BBATCH;                 // B
static const size_t OFF_SNM    = OFF_RB     + BBATCH;                 // NTOT
static const size_t OFF_PROTOT = OFF_SNM    + NTOT;                   // C*D
static const size_t OFF_CVAL   = OFF_PROTOT + (size_t)CCLS*DDIM;      // B*40
static const size_t OFF_CIDX   = OFF_CVAL   + (size_t)BBATCH*40;      // B*40 (int)
static const size_t OFF_ZERO   = OFF_CIDX   + (size_t)BBATCH*40;      // zeroed region:
static const size_t OFF_MACC   = OFF_ZERO;                            // C
static const size_t OFF_PMACC  = OFF_MACC   + CCLS;                   // C
static const size_t OFF_COLS   = OFF_PMACC  + CCLS;                   // C
static const size_t OFF_SCAL   = OFF_COLS   + CCLS;                   // 32
static const size_t OFF_PROTUN = OFF_SCAL   + 32;                     // D*C
static const size_t WS_END     = OFF_PROTUN + (size_t)DDIM*CCLS;

// ---------------- helpers ----------------
__device__ __forceinline__ float waveSum(float v){
  #pragma unroll
  for (int o = 32; o > 0; o >>= 1) v += __shfl_xor(v, o);
  return v;
}
__device__ __forceinline__ float waveMax(float v){
  #pragma unroll
  for (int o = 32; o > 0; o >>= 1) v = fmaxf(v, __shfl_xor(v, o));
  return v;
}
__device__ __forceinline__ float blockSum256(float v, float* sh4){
  v = waveSum(v);
  if ((threadIdx.x & 63) == 0) sh4[threadIdx.x >> 6] = v;
  __syncthreads();
  float r = sh4[0] + sh4[1] + sh4[2] + sh4[3];
  __syncthreads();
  return r;
}
// branchless stable top-5 insertion (strict > keeps earlier index on ties,
// matching jax.lax.top_k tie-breaking since streams are scanned in ascending n)
__device__ __forceinline__ void top5_insert(float* v, int* ix, float s, int si){
  bool c0 = s > v[0], c1 = s > v[1], c2 = s > v[2], c3 = s > v[3], c4 = s > v[4];
  v[4] = c4 ? (c3 ? v[3] : s) : v[4];  ix[4] = c4 ? (c3 ? ix[3] : si) : ix[4];
  v[3] = c3 ? (c2 ? v[2] : s) : v[3];  ix[3] = c3 ? (c2 ? ix[2] : si) : ix[3];
  v[2] = c2 ? (c1 ? v[1] : s) : v[2];  ix[2] = c2 ? (c1 ? ix[1] : si) : ix[2];
  v[1] = c1 ? (c0 ? v[0] : s) : v[1];  ix[1] = c1 ? (c0 ? ix[0] : si) : ix[1];
  v[0] = c0 ? s : v[0];                ix[0] = c0 ? si : ix[0];
}

// ---------------- 1. per-row input-energy entropy ----------------
__global__ __launch_bounds__(256)
void k_entropy(const float* __restrict__ x, float* __restrict__ e_row,
               float* __restrict__ scal){
  __shared__ __align__(16) float lx[LLEN];
  __shared__ float sh4[4];
  int row = blockIdx.x, t = threadIdx.x;
  const float4* xr = (const float4*)(x + (size_t)row * LLEN);
  float s = 0.f;
  #pragma unroll
  for (int i = 0; i < 4; ++i){
    float4 v = xr[t + 256*i];
    ((float4*)lx)[t + 256*i] = v;
    s += v.x*v.x + v.y*v.y + v.z*v.z + v.w*v.w;
  }
  s = blockSum256(s, sh4);
  float inv = 1.0f / fmaxf(s, FEPS);
  float ent = 0.f;
  #pragma unroll
  for (int i = 0; i < 4; ++i){
    float4 v = ((float4*)lx)[t + 256*i];
    float p;
    p = v.x*v.x*inv; ent -= p * logf(p + 1e-30f);
    p = v.y*v.y*inv; ent -= p * logf(p + 1e-30f);
    p = v.z*v.z*inv; ent -= p * logf(p + 1e-30f);
    p = v.w*v.w*inv; ent -= p * logf(p + 1e-30f);
  }
  ent = blockSum256(ent, sh4);
  if (t == 0){ e_row[row] = ent; atomicAdd(&scal[SC_SUME], ent); }
}

// ---------------- 2. feats = x @ Wf  (fp32, 128x128x16 tile) ----------------
#define GF_S 132   // LDS row stride (pad: 132 % 32 == 4 -> <=2-way bank aliasing)
__global__ __launch_bounds__(256)
void k_gemm_feats(const float* __restrict__ X, const float* __restrict__ Wf,
                  float* __restrict__ feats){
  __shared__ __align__(16) float At[16*GF_S];   // k-major x tile [16][128]
  __shared__ __align__(16) float Bt[16*GF_S];   // Wf tile [16][128]
  int t = threadIdx.x;
  int bn0 = blockIdx.x * 128;
  int bm0 = blockIdx.y * 128;
  int m0 = 8*(t & 7) + 64*(t >> 7);      // wave spans 8 m-groups -> 2-way LDS
  int n0 = 8*((t >> 3) & 15);
  int la_m = t >> 2;
  int la_k = (t & 3) * 4;
  int lb_k = t >> 5;
  int lb_n = (t & 31) * 4;
  float acc[8][8];
  #pragma unroll
  for (int i=0;i<8;++i){
    #pragma unroll
    for (int j=0;j<8;++j) acc[i][j]=0.f;
  }
  const float* xp0 = X  + (size_t)(bm0 + la_m)      * LLEN + la_k;
  const float* xp1 = X  + (size_t)(bm0 + la_m + 64) * LLEN + la_k;
  const float* wp0 = Wf + (size_t)lb_k       * DDIM + bn0 + lb_n;
  const float* wp1 = Wf + (size_t)(lb_k + 8) * DDIM + bn0 + lb_n;
  for (int k0 = 0; k0 < LLEN; k0 += 16){
    float4 a0 = *(const float4*)(xp0 + k0);
    float4 a1 = *(const float4*)(xp1 + k0);
    float4 b0 = *(const float4*)(wp0 + (size_t)k0 * DDIM);
    float4 b1 = *(const float4*)(wp1 + (size_t)k0 * DDIM);
    __syncthreads();
    At[(la_k+0)*GF_S + la_m] = a0.x;
    At[(la_k+1)*GF_S + la_m] = a0.y;
    At[(la_k+2)*GF_S + la_m] = a0.z;
    At[(la_k+3)*GF_S + la_m] = a0.w;
    At[(la_k+0)*GF_S + la_m + 64] = a1.x;
    At[(la_k+1)*GF_S + la_m + 64] = a1.y;
    At[(la_k+2)*GF_S + la_m + 64] = a1.z;
    At[(la_k+3)*GF_S + la_m + 64] = a1.w;
    *(float4*)&Bt[lb_k*GF_S + lb_n] = b0;
    *(float4*)&Bt[(lb_k+8)*GF_S + lb_n] = b1;
    __syncthreads();
    #pragma unroll
    for (int kk = 0; kk < 16; ++kk){
      float4 aA = *(float4*)&At[kk*GF_S + m0];
      float4 aB = *(float4*)&At[kk*GF_S + m0 + 4];
      float4 bA = *(float4*)&Bt[kk*GF_S + n0];
      float4 bB = *(float4*)&Bt[kk*GF_S + n0 + 4];
      float am[8] = {aA.x,aA.y,aA.z,aA.w,aB.x,aB.y,aB.z,aB.w};
      float bn[8] = {bA.x,bA.y,bA.z,bA.w,bB.x,bB.y,bB.z,bB.w};
      #pragma unroll
      for (int i=0;i<8;++i){
        #pragma unroll
        for (int j=0;j<8;++j) acc[i][j] = fmaf(am[i], bn[j], acc[i][j]);
      }
    }
  }
  #pragma unroll
  for (int i=0;i<8;++i){
    float* op = feats + (size_t)(bm0+m0+i)*DDIM + bn0 + n0;
    *(float4*)op     = make_float4(acc[i][0],acc[i][1],acc[i][2],acc[i][3]);
    *(float4*)(op+4) = make_float4(acc[i][4],acc[i][5],acc[i][6],acc[i][7]);
  }
}

// ---------------- 3. support row norms ----------------
__global__ __launch_bounds__(256)
void k_supnorm(const float* __restrict__ sup, float* __restrict__ snorm){
  int w = threadIdx.x >> 6, lane = threadIdx.x & 63;
  int row = blockIdx.x*4 + w;
  const float4* rp = (const float4*)(sup + (size_t)row * DDIM);
  float s = 0.f;
  #pragma unroll
  for (int j=0;j<4;++j){
    float4 v = rp[lane + 64*j];
    s += v.x*v.x+v.y*v.y+v.z*v.z+v.w*v.w;
  }
  s = waveSum(s);
  if (lane==0) snorm[row] = sqrtf(s);
}

// ---------------- 4. logits + softmax + argmax + feat norms ----------------
__global__ __launch_bounds__(256)
void k_logits(const float* __restrict__ feats, const float* __restrict__ Wc,
              const float* __restrict__ bc, float* __restrict__ probs,
              float* __restrict__ logp, float* __restrict__ pmax,
              int* __restrict__ pred, float* __restrict__ fnorm,
              float* __restrict__ scal){
  __shared__ __align__(16) float f[DDIM];
  __shared__ float z[CCLS];
  __shared__ float sh4[4];
  int row = blockIdx.x, t = threadIdx.x;
  const float4* fr = (const float4*)(feats + (size_t)row * DDIM);
  float ss = 0.f;
  { float4 v = fr[t]; ((float4*)f)[t] = v; ss += v.x*v.x+v.y*v.y+v.z*v.z+v.w*v.w; }
  ss = blockSum256(ss, sh4);
  if (t==0) fnorm[row] = sqrtf(ss);
  int w = t >> 6, lane = t & 63;
  for (int ci = 0; ci < 16; ++ci){
    int c = w*16 + ci;
    const float4* wc = (const float4*)(Wc + (size_t)c * DDIM);
    float d = 0.f;
    #pragma unroll
    for (int j=0;j<4;++j){
      float4 a = wc[lane + 64*j];
      float4 b = ((float4*)f)[lane + 64*j];
      d += a.x*b.x+a.y*b.y+a.z*b.z+a.w*b.w;
    }
    d = waveSum(d);
    if (lane == 0) z[c] = d + bc[c];
  }
  __syncthreads();
  if (w == 0){
    float zz = z[lane];
    float m = waveMax(zz);
    unsigned long long bal = __ballot(zz == m);
    int am = __ffsll(bal) - 1;
    float ex = expf(zz - m);
    float sv = waveSum(ex);
    probs[(size_t)row*CCLS + lane] = ex / sv;
    logp[(size_t)row*CCLS + lane]  = (zz - m) - logf(sv);
    if (lane == 0){
      float pmv = 1.0f / sv;          // max prob = exp(0)/sum
      pmax[row] = pmv;
      pred[row] = am;
      atomicAdd(&scal[SC_SUMP], pmv);
    }
  }
}

// ---------------- 5. masks, scale factors, colsum(feats part) ----------------
__global__ __launch_bounds__(256)
void k_mask(const float* __restrict__ e_row, const float* __restrict__ pmax,
            const float* __restrict__ fnorm, const float* __restrict__ snorm,
            const int* __restrict__ pred, float* __restrict__ w_c,
            float* __restrict__ rb, float* __restrict__ snm,
            float* __restrict__ colsum, float* __restrict__ scal){
  int i = blockIdx.x * 256 + threadIdx.x;
  if (i < NSUP) snm[i] = 1.0f / fmaxf(snorm[i], FEPS);
  if (i < BBATCH){
    float me = scal[SC_SUME] * (1.0f/BBATCH);
    float mp = scal[SC_SUMP] * (1.0f/BBATCH);
    float wc = ((e_row[i] < me) && (pmax[i] >= mp)) ? 1.0f : 0.0f;
    w_c[i] = wc;
    float fn = fmaxf(fnorm[i], FEPS);
    rb[i] = 10.0f / fn;                               // (1/TEMP)/||f||
    snm[NSUP + i] = (wc > 0.f) ? (1.0f / fn) : -1.0f; // sign = w_all>0 mask
    atomicAdd(&scal[SC_SUMWC], wc);
    atomicAdd(&colsum[pred[i]], wc);
  }
}

// ---------------- 6. colsum over labels_old ----------------
__global__ __launch_bounds__(256)
void k_colsum_labels(const float* __restrict__ labels, float* __restrict__ colsum){
  int t = threadIdx.x, c = t & 63, sub = t >> 6;
  int r0 = blockIdx.x * 256;
  float s = 0.f;
  for (int i = 0; i < 64; ++i){
    int r = r0 + sub + 4*i;
    s += labels[(size_t)r*CCLS + c];
  }
  __shared__ float loc[4][64];
  loc[sub][c] = s;
  __syncthreads();
  if (sub == 0) atomicAdd(&colsum[c], loc[0][c]+loc[1][c]+loc[2][c]+loc[3][c]);
}

// ---------------- 7. m accumulator (weighted prob column sums) ----------------
__global__ __launch_bounds__(256)
void k_m_accum(const float* __restrict__ probs, const float* __restrict__ w_c,
               float* __restrict__ m_acc){
  int t = threadIdx.x, c = t & 63, sub = t >> 6;
  int r0 = blockIdx.x * 64;
  float s = 0.f;
  for (int i = 0; i < 16; ++i){
    int r = r0 + sub + 4*i;
    s += probs[(size_t)r*CCLS + c] * w_c[r];
  }
  __shared__ float loc[4][64];
  loc[sub][c] = s;
  __syncthreads();
  if (sub == 0) atomicAdd(&m_acc[c], loc[0][c]+loc[1][c]+loc[2][c]+loc[3][c]);
}

// ---------------- 8. loss1 pieces (tsallis + pm accumulation) ----------------
__global__ __launch_bounds__(256)
void k_loss1(const float* __restrict__ probs, const float* __restrict__ m_acc,
             float* __restrict__ pm_acc, float* __restrict__ scal){
  int t = threadIdx.x, w = t >> 6, lane = t & 63;
  float swc = fmaxf(scal[SC_SUMWC], 1.0f);
  float minv = 1.0f / fmaxf(m_acc[lane] / swc, FEPS);
  float pml = 0.f, tsl = 0.f;
  int r0 = blockIdx.x * 64 + w * 16;
  for (int i = 0; i < 16; ++i){
    int r = r0 + i;
    float pb = probs[(size_t)r*CCLS + lane] * minv;
    float t1 = waveSum(pb);
    float t2 = waveSum(pb*pb);
    tsl += 1.0f - t2/(t1*t1);
    pml += pb/t1;
  }
  atomicAdd(&pm_acc[lane], pml);
  if (lane == 0) atomicAdd(&scal[SC_TSAL], tsl);
}

// ---------------- 9. protos GEMM: protos_un = sup_all^T @ lw2 ----------------
__global__ __launch_bounds__(256)
void k_protos_gemm(const float* __restrict__ sup, const float* __restrict__ feats,
                   const float* __restrict__ labels, const int* __restrict__ pred,
                   const float* __restrict__ w_c, const float* __restrict__ snm,
                   float* __restrict__ protos_un){
  __shared__ __align__(16) float ssx[64*68];
  __shared__ __align__(16) float sl[64*68];
  int t = threadIdx.x;
  int d0 = blockIdx.x * 64;
  int nbase = blockIdx.y * 1536;
  int dg = t & 15, cg = t >> 4;
  float acc[4][4];
  #pragma unroll
  for (int i=0;i<4;++i){
    #pragma unroll
    for (int j=0;j<4;++j) acc[i][j]=0.f;
  }
  for (int n0 = 0; n0 < 1536; n0 += 64){
    __syncthreads();
    #pragma unroll
    for (int i = 0; i < 4; ++i){
      int fidx = t + 256*i;
      int r = fidx >> 4;
      int dc = (fidx & 15) * 4;
      int n = nbase + n0 + r;
      const float* rp = (n < NSUP) ? (sup + (size_t)n*DDIM)
                                   : (feats + (size_t)(n-NSUP)*DDIM);
      *(float4*)&ssx[r*68 + dc] = *(const float4*)(rp + d0 + dc);
    }
    #pragma unroll
    for (int i = 0; i < 4; ++i){
      int fidx = t + 256*i;
      int r = fidx >> 4;
      int cc = (fidx & 15) * 4;
      int n = nbase + n0 + r;
      float sc = snm[n];
      float4 v;
      if (n < NSUP){
        float4 lb = *(const float4*)(labels + (size_t)n*CCLS + cc);
        v.x = lb.x*sc; v.y = lb.y*sc; v.z = lb.z*sc; v.w = lb.w*sc;
      } else {
        int b = n - NSUP;
        float base = w_c[b] * sc;    // 0 when uncertain (sc sign irrelevant)
        int p = pred[b];
        v.x = (p == cc+0) ? base : 0.f;
        v.y = (p == cc+1) ? base : 0.f;
        v.z = (p == cc+2) ? base : 0.f;
        v.w = (p == cc+3) ? base : 0.f;
      }
      *(float4*)&sl[r*68 + cc] = v;
    }
    __syncthreads();
    #pragma unroll 4
    for (int kk = 0; kk < 64; ++kk){
      float4 a = *(float4*)&ssx[kk*68 + 4*dg];
      float4 b = *(float4*)&sl[kk*68 + 4*cg];
      float av[4] = {a.x,a.y,a.z,a.w};
      float bv[4] = {b.x,b.y,b.z,b.w};
      #pragma unroll
      for (int i=0;i<4;++i){
        #pragma unroll
        for (int j=0;j<4;++j) acc[i][j] = fmaf(av[i], bv[j], acc[i][j]);
      }
    }
  }
  #pragma unroll
  for (int i=0;i<4;++i){
    #pragma unroll
    for (int j=0;j<4;++j)
      atomicAdd(&protos_un[(size_t)(d0 + 4*dg + i)*CCLS + 4*cg + j], acc[i][j]);
  }
}

// ---------------- 10. protos normalize (cols over D) -> [C][D] ----------------
__global__ __launch_bounds__(256)
void k_protos_norm(const float* __restrict__ protos_un, const float* __restrict__ colsum,
                   float* __restrict__ protos_t){
  int c = blockIdx.x, t = threadIdx.x;
  __shared__ float sh4[4];
  float cs = fmaxf(colsum[c], FEPS);
  float v[4];
  float ss = 0.f;
  #pragma unroll
  for (int i=0;i<4;++i){
    int d = t + 256*i;
    v[i] = protos_un[(size_t)d*CCLS + c] / cs;
    ss += v[i]*v[i];
  }
  ss = blockSum256(ss, sh4);
  float inv = 1.0f / fmaxf(sqrtf(ss), FEPS);
  #pragma unroll
  for (int i=0;i<4;++i){
    int d = t + 256*i;
    protos_t[(size_t)c*DDIM + d] = v[i]*inv;
  }
}

// ---------------- 11. loss2: prototype CE on certain rows ----------------
__global__ __launch_bounds__(256)
void k_loss2(const float* __restrict__ feats, const float* __restrict__ protos_t,
             const int* __restrict__ pred, const float* __restrict__ w_c,
             const float* __restrict__ fnorm, float* __restrict__ scal){
  int row = blockIdx.x, t = threadIdx.x;
  float wc = w_c[row];
  if (wc == 0.f) return;          // uniform per block; rows with w_c=0 contribute 0
  __shared__ __align__(16) float f[DDIM];
  __shared__ float z[CCLS];
  float inv = 1.0f / fmaxf(fnorm[row], FEPS);
  { float4 v = ((const float4*)(feats + (size_t)row*DDIM))[t];
    v.x*=inv; v.y*=inv; v.z*=inv; v.w*=inv;
    ((float4*)f)[t] = v; }
  __syncthreads();
  int w = t >> 6, lane = t & 63;
  for (int ci=0; ci<16; ++ci){
    int c = w*16+ci;
    const float4* pc = (const float4*)(protos_t + (size_t)c*DDIM);
    float d = 0.f;
    #pragma unroll
    for (int j=0;j<4;++j){
      float4 a = pc[lane + 64*j];
      float4 b = ((float4*)f)[lane + 64*j];
      d += a.x*b.x+a.y*b.y+a.z*b.z+a.w*b.w;
    }
    d = waveSum(d);
    if (lane==0) z[c] = d;
  }
  __syncthreads();
  if (w == 0){
    float zz = z[lane];
    float m = waveMax(zz);
    float sv = waveSum(expf(zz - m));
    if (lane == 0){
      float lse = m + logf(sv);
      float ce = lse - z[pred[row]];
      atomicAdd(&scal[SC_L2NUM], ce * wc);
    }
  }
}

// ---------------- 12. fused sim GEMM + per-chunk top-5 ----------------
// grid (64 b-blocks, 8 n-chunks); 64 b-rows x 1536 n per block, 4b x 8n per thread
__global__ __launch_bounds__(256)
void k_sim_topk(const float* __restrict__ feats, const float* __restrict__ sup,
                const float* __restrict__ rb, const float* __restrict__ snm,
                float* __restrict__ cval, int* __restrict__ cidx){
  __shared__ __align__(16) float smem[10240];   // 40KB: tiles then merge buffer
  float* At  = smem;                    // [16][68]  feats k-major
  float* Bt  = smem + 16*68;            // [16][132] sup k-major
  float* sns = smem + 16*68 + 16*132;   // [128]
  int t = threadIdx.x;
  int b0  = blockIdx.x * 64;
  int cn0 = blockIdx.y * 1536;
  int bg = t & 15, ng = t >> 4;
  float rbv[4];
  #pragma unroll
  for (int i=0;i<4;++i) rbv[i] = rb[b0 + 4*bg + i];
  float tv[4][5]; int ti[4][5];
  #pragma unroll
  for (int i=0;i<4;++i){
    #pragma unroll
    for (int k=0;k<5;++k){ tv[i][k] = -INFINITY; ti[i][k] = 0x7fffffff; }
  }
  int am = t >> 2;           // 0..63
  int ak = (t & 3) * 4;      // 0,4,8,12
  const float* ap = feats + (size_t)(b0 + am) * DDIM + ak;
  for (int nt = 0; nt < 12; ++nt){
    int nbase = cn0 + nt * 128;
    __syncthreads();                        // protect sns against stragglers
    if (t < 128) sns[t] = snm[nbase + t];
    float acc[4][8];
    #pragma unroll
    for (int i=0;i<4;++i){
      #pragma unroll
      for (int j=0;j<8;++j) acc[i][j] = 0.f;
    }
    int n1 = nbase + am;
    int n2 = n1 + 64;
    const float* bp1 = ((n1 < NSUP) ? (sup + (size_t)n1*DDIM)
                                    : (feats + (size_t)(n1-NSUP)*DDIM)) + ak;
    const float* bp2 = ((n2 < NSUP) ? (sup + (size_t)n2*DDIM)
                                    : (feats + (size_t)(n2-NSUP)*DDIM)) + ak;
    for (int k0 = 0; k0 < DDIM; k0 += 16){
      float4 av = *(const float4*)(ap + k0);
      float4 b1 = *(const float4*)(bp1 + k0);
      float4 b2 = *(const float4*)(bp2 + k0);
      __syncthreads();
      At[(ak+0)*68 + am] = av.x;
      At[(ak+1)*68 + am] = av.y;
      At[(ak+2)*68 + am] = av.z;
      At[(ak+3)*68 + am] = av.w;
      Bt[(ak+0)*132 + am] = b1.x;
      Bt[(ak+1)*132 + am] = b1.y;
      Bt[(ak+2)*132 + am] = b1.z;
      Bt[(ak+3)*132 + am] = b1.w;
      Bt[(ak+0)*132 + am + 64] = b2.x;
      Bt[(ak+1)*132 + am + 64] = b2.y;
      Bt[(ak+2)*132 + am + 64] = b2.z;
      Bt[(ak+3)*132 + am + 64] = b2.w;
      __syncthreads();
      #pragma unroll
      for (int kk = 0; kk < 16; ++kk){
        float4 a  = *(float4*)&At[kk*68 + 4*bg];
        float4 x0 = *(float4*)&Bt[kk*132 + 8*ng];
        float4 x1 = *(float4*)&Bt[kk*132 + 8*ng + 4];
        float av4[4] = {a.x,a.y,a.z,a.w};
        float bv8[8] = {x0.x,x0.y,x0.z,x0.w,x1.x,x1.y,x1.z,x1.w};
        #pragma unroll
        for (int i=0;i<4;++i){
          #pragma unroll
          for (int j=0;j<8;++j) acc[i][j] = fmaf(av4[i], bv8[j], acc[i][j]);
        }
      }
    }
    #pragma unroll
    for (int j=0;j<8;++j){
      int nl = 8*ng + j;
      float s = sns[nl];
      float fa = fabsf(s);
      int ngl = nbase + nl;
      #pragma unroll
      for (int i=0;i<4;++i){
        float sim = acc[i][j] * rbv[i] * fa;
        sim = (s > 0.f) ? sim : -INFINITY;    // w_all mask
        top5_insert(tv[i], ti[i], sim, ngl);
      }
    }
  }
  __syncthreads();
  // in-block merge: per b-row, 16 threads x 5 candidates
  float* mv = smem;                 // [64][16][5]
  int*   mi = (int*)(smem + 5120);
  #pragma unroll
  for (int i=0;i<4;++i){
    int bl = 4*bg + i;
    #pragma unroll
    for (int k=0;k<5;++k){
      mv[(bl*16 + ng)*5 + k] = tv[i][k];
      mi[(bl*16 + ng)*5 + k] = ti[i][k];
    }
  }
  __syncthreads();
  if (t < 64){
    float bv[5]; int bi[5];
    #pragma unroll
    for (int k=0;k<5;++k){ bv[k] = -INFINITY; bi[k] = 0x7fffffff; }
    for (int j = 0; j < 80; ++j){
      top5_insert(bv, bi, mv[t*80 + j], mi[t*80 + j]);
    }
    float* co = cval + (size_t)(b0 + t)*40 + blockIdx.y*5;
    int*   ci = cidx + (size_t)(b0 + t)*40 + blockIdx.y*5;
    #pragma unroll
    for (int k=0;k<5;++k){ co[k] = bv[k]; ci[k] = bi[k]; }
  }
}

// ---------------- 13. cross-chunk merge + NCL ----------------
__global__ __launch_bounds__(256)
void k_merge_ncl(const float* __restrict__ cval, const int* __restrict__ cidx,
                 const float* __restrict__ scores_old, const float* __restrict__ probs,
                 const float* __restrict__ logp, const float* __restrict__ w_c,
                 float* __restrict__ scal){
  __shared__ float sv[4][40];
  __shared__ int   si[4][40];
  __shared__ int   top[4][5];
  int t = threadIdx.x, w = t >> 6, lane = t & 63;
  int b = blockIdx.x*4 + w;
  if (lane < 40){
    sv[w][lane] = cval[(size_t)b*40 + lane];
    si[w][lane] = cidx[(size_t)b*40 + lane];
  }
  __syncthreads();
  if (lane == 0){
    float bv[5]; int bi[5];
    #pragma unroll
    for (int k=0;k<5;++k){ bv[k] = -INFINITY; bi[k] = 0x7fffffff; }
    for (int j=0;j<40;++j) top5_insert(bv, bi, sv[w][j], si[w][j]);
    #pragma unroll
    for (int k=0;k<5;++k) top[w][k] = bi[k];
  }
  __syncthreads();
  float tg = 0.f;
  #pragma unroll
  for (int k=0;k<5;++k){
    int ix = top[w][k];
    const float* srow = (ix < NSUP) ? (scores_old + (size_t)ix*CCLS)
                                    : (probs + (size_t)(ix-NSUP)*CCLS);
    tg += srow[lane];
  }
  tg *= 0.2f;
  float d = tg * logp[(size_t)b*CCLS + lane];
  d = waveSum(d);
  if (lane == 0) atomicAdd(&scal[SC_L3NUM], -d * (1.0f - w_c[b]));
}

// ---------------- 14. final combine ----------------
__global__ void k_final(const float* __restrict__ pm_acc, const float* __restrict__ scal,
                        float* __restrict__ out){
  int lane = threadIdx.x;  // 64 threads
  float pm = pm_acc[lane] * (1.0f/BBATCH);
  float dterm = pm * logf(pm + FEPS);
  float dv = waveSum(dterm);
  if (lane == 0){
    float div = -dv;
    float tsallis = scal[SC_TSAL] * (1.0f/BBATCH);
    float swc = scal[SC_SUMWC];
    float l1 = tsallis - div;
    float l2 = scal[SC_L2NUM] / fmaxf(swc, 1.0f);
    float l3 = scal[SC_L3NUM] / fmaxf((float)BBATCH - swc, 1.0f);
    out[0] = l1 + l2 + l3;
  }
}

// ---------------- launch ----------------
extern "C" void kernel_launch(void* const* d_in, const int* in_sizes, int n_in,
                              void* d_out, int out_size, void* d_ws, size_t ws_size,
                              hipStream_t stream){
  (void)in_sizes; (void)n_in; (void)out_size; (void)ws_size;
  const float* x      = (const float*)d_in[0];
  // d_in[1] = y (unused by the reference loss)
  const float* Wf     = (const float*)d_in[2];
  const float* Wc     = (const float*)d_in[3];
  const float* bc     = (const float*)d_in[4];
  const float* sup    = (const float*)d_in[5];
  const float* labels = (const float*)d_in[6];
  const float* scores = (const float*)d_in[7];
  float* ws = (float*)d_ws;

  float* feats  = ws + OFF_FEATS;
  float* probs  = ws + OFF_PROBS;
  float* logp   = ws + OFF_LOGP;
  float* fnorm  = ws + OFF_FNORM;
  float* snorm  = ws + OFF_SNORM;
  float* pmax   = ws + OFF_PMAX;
  float* e_row  = ws + OFF_EROW;
  float* w_c    = ws + OFF_WC;
  int*   pred   = (int*)(ws + OFF_PRED);
  float* rb     = ws + OFF_RB;
  float* snm    = ws + OFF_SNM;
  float* protot = ws + OFF_PROTOT;
  float* cvalp  = ws + OFF_CVAL;
  int*   cidxp  = (int*)(ws + OFF_CIDX);
  float* m_acc  = ws + OFF_MACC;
  float* pm_acc = ws + OFF_PMACC;
  float* colsum = ws + OFF_COLS;
  float* scal   = ws + OFF_SCAL;
  float* protun = ws + OFF_PROTUN;

  hipMemsetAsync(ws + OFF_ZERO, 0, (WS_END - OFF_ZERO)*sizeof(float), stream);

  k_entropy      <<<BBATCH, 256, 0, stream>>>(x, e_row, scal);
  k_gemm_feats   <<<dim3(DDIM/128, BBATCH/128), 256, 0, stream>>>(x, Wf, feats);
  k_supnorm      <<<NSUP/4, 256, 0, stream>>>(sup, snorm);
  k_logits       <<<BBATCH, 256, 0, stream>>>(feats, Wc, bc, probs, logp, pmax, pred, fnorm, scal);
  k_mask         <<<32, 256, 0, stream>>>(e_row, pmax, fnorm, snorm, pred, w_c, rb, snm, colsum, scal);
  k_colsum_labels<<<32, 256, 0, stream>>>(labels, colsum);
  k_m_accum      <<<64, 256, 0, stream>>>(probs, w_c, m_acc);
  k_loss1        <<<64, 256, 0, stream>>>(probs, m_acc, pm_acc, scal);
  k_protos_gemm  <<<dim3(16, 8), 256, 0, stream>>>(sup, feats, labels, pred, w_c, snm, protun);
  k_protos_norm  <<<CCLS, 256, 0, stream>>>(protun, colsum, protot);
  k_loss2        <<<BBATCH, 256, 0, stream>>>(feats, protot, pred, w_c, fnorm, scal);
  k_sim_topk     <<<dim3(BBATCH/64, 8), 256, 0, stream>>>(feats, sup, rb, snm, cvalp, cidxp);
  k_merge_ncl    <<<BBATCH/4, 256, 0, stream>>>(cvalp, cidxp, scores, probs, logp, w_c, scal);
  k_final        <<<1, 64, 0, stream>>>(pm_acc, scal, (float*)d_out);
}

// Round 2
// 1081.229 us; speedup vs baseline: 2.2035x; 2.2035x over previous
//
#include <hip/hip_runtime.h>
#include <math.h>

// ---------------- problem constants ----------------
#define BBATCH 4096
#define LLEN   4096
#define DDIM   1024
#define CCLS   64
#define NSUP   8192
#define NTOT   12288            // NSUP + BBATCH
#define FEPS   1e-12f
#define KCHUNK 96               // NTOT / 128 support chunks
#define KCAND  (KCHUNK*5)       // 480 candidates per row

// scalar accumulator slots
#define SC_SUMP  0
#define SC_SUME  1
#define SC_SUMWC 2
#define SC_TSAL  3
#define SC_L2NUM 4
#define SC_L3NUM 5

typedef _Float16 half4_t __attribute__((ext_vector_type(4)));
typedef _Float16 half8_t __attribute__((ext_vector_type(8)));
typedef float    f32x4   __attribute__((ext_vector_type(4)));

// ---------------- workspace layout (float offsets) ----------------
static const size_t OFF_FEATS  = 0;                                    // B*D (featp0; finalized by k_logits)
static const size_t OFF_FEATP1 = OFF_FEATS  + (size_t)BBATCH*DDIM;     // B*D
static const size_t OFF_WFTH   = OFF_FEATP1 + (size_t)BBATCH*DDIM;     // D*L halves = D*L/2 floats
static const size_t OFF_WFTL   = OFF_WFTH   + (size_t)DDIM*LLEN/2;
static const size_t OFF_PROBS  = OFF_WFTL   + (size_t)DDIM*LLEN/2;     // B*C
static const size_t OFF_LOGP   = OFF_PROBS  + (size_t)BBATCH*CCLS;     // B*C
static const size_t OFF_FNORM  = OFF_LOGP   + (size_t)BBATCH*CCLS;     // B
static const size_t OFF_SNORM  = OFF_FNORM  + BBATCH;                  // N
static const size_t OFF_PMAX   = OFF_SNORM  + NSUP;                    // B
static const size_t OFF_EROW   = OFF_PMAX   + BBATCH;                  // B
static const size_t OFF_WC     = OFF_EROW   + BBATCH;                  // B
static const size_t OFF_PRED   = OFF_WC     + BBATCH;                  // B (int)
static const size_t OFF_RB     = OFF_PRED   + BBATCH;                  // B
static const size_t OFF_SNM    = OFF_RB     + BBATCH;                  // NTOT
static const size_t OFF_PROTOT = OFF_SNM    + NTOT;                    // C*D
static const size_t OFF_CVAL   = OFF_PROTOT + (size_t)CCLS*DDIM;       // B*KCAND
static const size_t OFF_CIDX   = OFF_CVAL   + (size_t)BBATCH*KCAND;    // B*KCAND (int)
static const size_t OFF_ZERO   = OFF_CIDX   + (size_t)BBATCH*KCAND;    // zeroed region:
static const size_t OFF_MACC   = OFF_ZERO;                             // C
static const size_t OFF_PMACC  = OFF_MACC   + CCLS;                    // C
static const size_t OFF_COLS   = OFF_PMACC  + CCLS;                    // C
static const size_t OFF_SCAL   = OFF_COLS   + CCLS;                    // 32
static const size_t OFF_PROTUN = OFF_SCAL   + 32;                      // D*C
static const size_t WS_END     = OFF_PROTUN + (size_t)DDIM*CCLS;

// ---------------- helpers ----------------
__device__ __forceinline__ float waveSum(float v){
  #pragma unroll
  for (int o = 32; o > 0; o >>= 1) v += __shfl_xor(v, o);
  return v;
}
__device__ __forceinline__ float waveMax(float v){
  #pragma unroll
  for (int o = 32; o > 0; o >>= 1) v = fmaxf(v, __shfl_xor(v, o));
  return v;
}
__device__ __forceinline__ float blockSum256(float v, float* sh4){
  v = waveSum(v);
  if ((threadIdx.x & 63) == 0) sh4[threadIdx.x >> 6] = v;
  __syncthreads();
  float r = sh4[0] + sh4[1] + sh4[2] + sh4[3];
  __syncthreads();
  return r;
}
// branchless stable top-5 insertion (strict > keeps earlier-inserted on ties)
__device__ __forceinline__ void top5_insert(float* v, int* ix, float s, int si){
  bool c0 = s > v[0], c1 = s > v[1], c2 = s > v[2], c3 = s > v[3], c4 = s > v[4];
  v[4] = c4 ? (c3 ? v[3] : s) : v[4];  ix[4] = c4 ? (c3 ? ix[3] : si) : ix[4];
  v[3] = c3 ? (c2 ? v[2] : s) : v[3];  ix[3] = c3 ? (c2 ? ix[2] : si) : ix[3];
  v[2] = c2 ? (c1 ? v[1] : s) : v[2];  ix[2] = c2 ? (c1 ? ix[1] : si) : ix[2];
  v[1] = c1 ? (c0 ? v[0] : s) : v[1];  ix[1] = c1 ? (c0 ? ix[0] : si) : ix[1];
  v[0] = c0 ? s : v[0];                ix[0] = c0 ? si : ix[0];
}
// fp32 -> f16 hi + f16 lo (residual); hi+lo reproduces fp32 to ~2^-24
__device__ __forceinline__ void split4(const float4 v, half4_t* h, half4_t* l){
  half4_t hh, ll;
  hh[0] = (_Float16)v.x; hh[1] = (_Float16)v.y; hh[2] = (_Float16)v.z; hh[3] = (_Float16)v.w;
  ll[0] = (_Float16)(v.x - (float)hh[0]);
  ll[1] = (_Float16)(v.y - (float)hh[1]);
  ll[2] = (_Float16)(v.z - (float)hh[2]);
  ll[3] = (_Float16)(v.w - (float)hh[3]);
  *h = hh; *l = ll;
}

// ---------------- 1. per-row input-energy entropy ----------------
__global__ __launch_bounds__(256)
void k_entropy(const float* __restrict__ x, float* __restrict__ e_row,
               float* __restrict__ scal){
  __shared__ __align__(16) float lx[LLEN];
  __shared__ float sh4[4];
  int row = blockIdx.x, t = threadIdx.x;
  const float4* xr = (const float4*)(x + (size_t)row * LLEN);
  float s = 0.f;
  #pragma unroll
  for (int i = 0; i < 4; ++i){
    float4 v = xr[t + 256*i];
    ((float4*)lx)[t + 256*i] = v;
    s += v.x*v.x + v.y*v.y + v.z*v.z + v.w*v.w;
  }
  s = blockSum256(s, sh4);
  float inv = 1.0f / fmaxf(s, FEPS);
  float ent = 0.f;
  #pragma unroll
  for (int i = 0; i < 4; ++i){
    float4 v = ((float4*)lx)[t + 256*i];
    float p;
    p = v.x*v.x*inv; ent -= p * logf(p + 1e-30f);
    p = v.y*v.y*inv; ent -= p * logf(p + 1e-30f);
    p = v.z*v.z*inv; ent -= p * logf(p + 1e-30f);
    p = v.w*v.w*inv; ent -= p * logf(p + 1e-30f);
  }
  ent = blockSum256(ent, sh4);
  if (t == 0){ e_row[row] = ent; atomicAdd(&scal[SC_SUME], ent); }
}

// ---------------- 2a. Wf transpose + f16 split: Wft[d][l] hi/lo ----------------
__global__ __launch_bounds__(256)
void k_wft(const float* __restrict__ Wf, unsigned short* __restrict__ WftH,
           unsigned short* __restrict__ WftL){
  __shared__ __align__(16) float ld[64*68];
  int t = threadIdx.x;
  int d0 = blockIdx.x * 64;
  int l0 = blockIdx.y * 64;
  #pragma unroll
  for (int i = 0; i < 4; ++i){
    int flat = t + 256*i;
    int l = flat >> 4, d4 = (flat & 15) * 4;
    *(float4*)&ld[l*68 + d4] = *(const float4*)(Wf + (size_t)(l0+l)*DDIM + d0 + d4);
  }
  __syncthreads();
  #pragma unroll
  for (int i = 0; i < 4; ++i){
    int flat = t + 256*i;
    int d = flat >> 4, l4 = (flat & 15) * 4;
    float4 v = make_float4(ld[(l4+0)*68 + d], ld[(l4+1)*68 + d],
                           ld[(l4+2)*68 + d], ld[(l4+3)*68 + d]);
    half4_t h, l;
    split4(v, &h, &l);
    *(half4_t*)(WftH + (size_t)(d0+d)*LLEN + l0 + l4) = h;
    *(half4_t*)(WftL + (size_t)(d0+d)*LLEN + l0 + l4) = l;
  }
}

// ---------------- 2b. feats = x @ Wf via f16x3 MFMA, K-split x2 ----------------
// block 128m x 128n, BK=32, 4 waves 2x2 (wave tile 64x64), 16x16x32 frags
#define LP 40   // LDS row pitch in halves (32 + 8 pad)
__global__ __launch_bounds__(256)
void k_feats_mfma(const float* __restrict__ X, const unsigned short* __restrict__ WftH,
                  const unsigned short* __restrict__ WftL, float* __restrict__ featp){
  __shared__ __align__(16) _Float16 lds[4*128*LP];   // Ah|Al|Bh|Bl = 40KB
  _Float16* Ah = lds;
  _Float16* Al = lds + 128*LP;
  _Float16* Bh = lds + 2*128*LP;
  _Float16* Bl = lds + 3*128*LP;
  int t = threadIdx.x;
  int n0 = blockIdx.x * 128;
  int m0 = blockIdx.y * 128;
  int kz = blockIdx.z;                 // K-split half
  int w = t >> 6, lane = t & 63;
  int wr = w >> 1, wc = w & 1;
  int lr = lane & 15, lg = lane >> 4;
  int ar = t >> 3, akq = (t & 7);      // A stage: row, float4-idx (x4 iters, +32 rows)
  int br = t >> 2, bk8 = (t & 3) * 8;  // B stage: row (x2 iters, +64 rows), 8-half chunk
  f32x4 acc[4][4];
  #pragma unroll
  for (int i=0;i<4;++i){
    #pragma unroll
    for (int j=0;j<4;++j) acc[i][j] = (f32x4)(0.f);
  }
  for (int k0 = kz*2048; k0 < kz*2048 + 2048; k0 += 32){
    // global loads first (overlap prior compute)
    float4 av[4]; uint4 bhv[2], blv[2];
    #pragma unroll
    for (int i=0;i<4;++i)
      av[i] = *(const float4*)(X + (size_t)(m0 + ar + 32*i)*LLEN + k0 + akq*4);
    #pragma unroll
    for (int i=0;i<2;++i){
      bhv[i] = *(const uint4*)(WftH + (size_t)(n0 + br + 64*i)*LLEN + k0 + bk8);
      blv[i] = *(const uint4*)(WftL + (size_t)(n0 + br + 64*i)*LLEN + k0 + bk8);
    }
    __syncthreads();
    #pragma unroll
    for (int i=0;i<4;++i){
      half4_t h, l;
      split4(av[i], &h, &l);
      *(half4_t*)&Ah[(ar + 32*i)*LP + akq*4] = h;
      *(half4_t*)&Al[(ar + 32*i)*LP + akq*4] = l;
    }
    #pragma unroll
    for (int i=0;i<2;++i){
      *(uint4*)&Bh[(br + 64*i)*LP + bk8] = bhv[i];
      *(uint4*)&Bl[(br + 64*i)*LP + bk8] = blv[i];
    }
    __syncthreads();
    half8_t ah[4], al[4], bh[4], bl[4];
    #pragma unroll
    for (int mi=0;mi<4;++mi){
      const _Float16* p = &Ah[(wr*64 + mi*16 + lr)*LP + lg*8];
      ah[mi] = *(const half8_t*)p;
      al[mi] = *(const half8_t*)(p + 128*LP);
    }
    #pragma unroll
    for (int ni=0;ni<4;++ni){
      const _Float16* p = &Bh[(wc*64 + ni*16 + lr)*LP + lg*8];
      bh[ni] = *(const half8_t*)p;
      bl[ni] = *(const half8_t*)(p + 128*LP);
    }
    #pragma unroll
    for (int mi=0;mi<4;++mi){
      #pragma unroll
      for (int ni=0;ni<4;++ni){
        acc[mi][ni] = __builtin_amdgcn_mfma_f32_16x16x32_f16(ah[mi], bh[ni], acc[mi][ni], 0,0,0);
        acc[mi][ni] = __builtin_amdgcn_mfma_f32_16x16x32_f16(ah[mi], bl[ni], acc[mi][ni], 0,0,0);
        acc[mi][ni] = __builtin_amdgcn_mfma_f32_16x16x32_f16(al[mi], bh[ni], acc[mi][ni], 0,0,0);
      }
    }
  }
  float* outp = featp + (size_t)kz * BBATCH * DDIM;
  #pragma unroll
  for (int mi=0;mi<4;++mi){
    #pragma unroll
    for (int ni=0;ni<4;++ni){
      #pragma unroll
      for (int r=0;r<4;++r){
        int row = m0 + wr*64 + mi*16 + lg*4 + r;
        int col = n0 + wc*64 + ni*16 + lr;
        outp[(size_t)row*DDIM + col] = acc[mi][ni][r];
      }
    }
  }
}

// ---------------- 3. support row norms ----------------
__global__ __launch_bounds__(256)
void k_supnorm(const float* __restrict__ sup, float* __restrict__ snorm){
  int w = threadIdx.x >> 6, lane = threadIdx.x & 63;
  int row = blockIdx.x*4 + w;
  const float4* rp = (const float4*)(sup + (size_t)row * DDIM);
  float s = 0.f;
  #pragma unroll
  for (int j=0;j<4;++j){
    float4 v = rp[lane + 64*j];
    s += v.x*v.x+v.y*v.y+v.z*v.z+v.w*v.w;
  }
  s = waveSum(s);
  if (lane==0) snorm[row] = sqrtf(s);
}

// ---------------- 4. sum K-split partials -> feats; logits+softmax+argmax ----------------
__global__ __launch_bounds__(256)
void k_logits(float* __restrict__ feats, const float* __restrict__ featp1,
              const float* __restrict__ Wc,
              const float* __restrict__ bc, float* __restrict__ probs,
              float* __restrict__ logp, float* __restrict__ pmax,
              int* __restrict__ pred, float* __restrict__ fnorm,
              float* __restrict__ scal){
  __shared__ __align__(16) float f[DDIM];
  __shared__ float z[CCLS];
  __shared__ float sh4[4];
  int row = blockIdx.x, t = threadIdx.x;
  const float4* fr0 = (const float4*)(feats  + (size_t)row * DDIM);
  const float4* fr1 = (const float4*)(featp1 + (size_t)row * DDIM);
  float ss = 0.f;
  { float4 a = fr0[t], b = fr1[t];
    float4 v = make_float4(a.x+b.x, a.y+b.y, a.z+b.z, a.w+b.w);
    ((float4*)f)[t] = v;
    ((float4*)(feats + (size_t)row*DDIM))[t] = v;
    ss += v.x*v.x+v.y*v.y+v.z*v.z+v.w*v.w; }
  ss = blockSum256(ss, sh4);
  if (t==0) fnorm[row] = sqrtf(ss);
  int w = t >> 6, lane = t & 63;
  for (int ci = 0; ci < 16; ++ci){
    int c = w*16 + ci;
    const float4* wc = (const float4*)(Wc + (size_t)c * DDIM);
    float d = 0.f;
    #pragma unroll
    for (int j=0;j<4;++j){
      float4 a = wc[lane + 64*j];
      float4 b = ((float4*)f)[lane + 64*j];
      d += a.x*b.x+a.y*b.y+a.z*b.z+a.w*b.w;
    }
    d = waveSum(d);
    if (lane == 0) z[c] = d + bc[c];
  }
  __syncthreads();
  if (w == 0){
    float zz = z[lane];
    float m = waveMax(zz);
    unsigned long long bal = __ballot(zz == m);
    int am = __ffsll(bal) - 1;
    float ex = expf(zz - m);
    float sv = waveSum(ex);
    probs[(size_t)row*CCLS + lane] = ex / sv;
    logp[(size_t)row*CCLS + lane]  = (zz - m) - logf(sv);
    if (lane == 0){
      float pmv = 1.0f / sv;
      pmax[row] = pmv;
      pred[row] = am;
      atomicAdd(&scal[SC_SUMP], pmv);
    }
  }
}

// ---------------- 5. masks, scale factors, colsum(feats part) ----------------
__global__ __launch_bounds__(256)
void k_mask(const float* __restrict__ e_row, const float* __restrict__ pmax,
            const float* __restrict__ fnorm, const float* __restrict__ snorm,
            const int* __restrict__ pred, float* __restrict__ w_c,
            float* __restrict__ rb, float* __restrict__ snm,
            float* __restrict__ colsum, float* __restrict__ scal){
  int i = blockIdx.x * 256 + threadIdx.x;
  if (i < NSUP) snm[i] = 1.0f / fmaxf(snorm[i], FEPS);
  if (i < BBATCH){
    float me = scal[SC_SUME] * (1.0f/BBATCH);
    float mp = scal[SC_SUMP] * (1.0f/BBATCH);
    float wc = ((e_row[i] < me) && (pmax[i] >= mp)) ? 1.0f : 0.0f;
    w_c[i] = wc;
    float fn = fmaxf(fnorm[i], FEPS);
    rb[i] = 10.0f / fn;                               // (1/TEMP)/||f||
    snm[NSUP + i] = (wc > 0.f) ? (1.0f / fn) : -1.0f; // sign = w_all>0 mask
    atomicAdd(&scal[SC_SUMWC], wc);
    atomicAdd(&colsum[pred[i]], wc);
  }
}

// ---------------- 6. colsum over labels_old ----------------
__global__ __launch_bounds__(256)
void k_colsum_labels(const float* __restrict__ labels, float* __restrict__ colsum){
  int t = threadIdx.x, c = t & 63, sub = t >> 6;
  int r0 = blockIdx.x * 256;
  float s = 0.f;
  for (int i = 0; i < 64; ++i){
    int r = r0 + sub + 4*i;
    s += labels[(size_t)r*CCLS + c];
  }
  __shared__ float loc[4][64];
  loc[sub][c] = s;
  __syncthreads();
  if (sub == 0) atomicAdd(&colsum[c], loc[0][c]+loc[1][c]+loc[2][c]+loc[3][c]);
}

// ---------------- 7. m accumulator (weighted prob column sums) ----------------
__global__ __launch_bounds__(256)
void k_m_accum(const float* __restrict__ probs, const float* __restrict__ w_c,
               float* __restrict__ m_acc){
  int t = threadIdx.x, c = t & 63, sub = t >> 6;
  int r0 = blockIdx.x * 64;
  float s = 0.f;
  for (int i = 0; i < 16; ++i){
    int r = r0 + sub + 4*i;
    s += probs[(size_t)r*CCLS + c] * w_c[r];
  }
  __shared__ float loc[4][64];
  loc[sub][c] = s;
  __syncthreads();
  if (sub == 0) atomicAdd(&m_acc[c], loc[0][c]+loc[1][c]+loc[2][c]+loc[3][c]);
}

// ---------------- 8. loss1 pieces (tsallis + pm accumulation) ----------------
__global__ __launch_bounds__(256)
void k_loss1(const float* __restrict__ probs, const float* __restrict__ m_acc,
             float* __restrict__ pm_acc, float* __restrict__ scal){
  int t = threadIdx.x, w = t >> 6, lane = t & 63;
  float swc = fmaxf(scal[SC_SUMWC], 1.0f);
  float minv = 1.0f / fmaxf(m_acc[lane] / swc, FEPS);
  float pml = 0.f, tsl = 0.f;
  int r0 = blockIdx.x * 64 + w * 16;
  for (int i = 0; i < 16; ++i){
    int r = r0 + i;
    float pb = probs[(size_t)r*CCLS + lane] * minv;
    float t1 = waveSum(pb);
    float t2 = waveSum(pb*pb);
    tsl += 1.0f - t2/(t1*t1);
    pml += pb/t1;
  }
  atomicAdd(&pm_acc[lane], pml);
  if (lane == 0) atomicAdd(&scal[SC_TSAL], tsl);
}

// ---------------- 9. protos GEMM: protos_un = sup_all^T @ lw2 ----------------
__global__ __launch_bounds__(256)
void k_protos_gemm(const float* __restrict__ sup, const float* __restrict__ feats,
                   const float* __restrict__ labels, const int* __restrict__ pred,
                   const float* __restrict__ w_c, const float* __restrict__ snm,
                   float* __restrict__ protos_un){
  __shared__ __align__(16) float ssx[64*68];
  __shared__ __align__(16) float sl[64*68];
  int t = threadIdx.x;
  int d0 = blockIdx.x * 64;
  int nbase = blockIdx.y * 1536;
  int dg = t & 15, cg = t >> 4;
  float acc[4][4];
  #pragma unroll
  for (int i=0;i<4;++i){
    #pragma unroll
    for (int j=0;j<4;++j) acc[i][j]=0.f;
  }
  for (int n0 = 0; n0 < 1536; n0 += 64){
    __syncthreads();
    #pragma unroll
    for (int i = 0; i < 4; ++i){
      int fidx = t + 256*i;
      int r = fidx >> 4;
      int dc = (fidx & 15) * 4;
      int n = nbase + n0 + r;
      const float* rp = (n < NSUP) ? (sup + (size_t)n*DDIM)
                                   : (feats + (size_t)(n-NSUP)*DDIM);
      *(float4*)&ssx[r*68 + dc] = *(const float4*)(rp + d0 + dc);
    }
    #pragma unroll
    for (int i = 0; i < 4; ++i){
      int fidx = t + 256*i;
      int r = fidx >> 4;
      int cc = (fidx & 15) * 4;
      int n = nbase + n0 + r;
      float sc = snm[n];
      float4 v;
      if (n < NSUP){
        float4 lb = *(const float4*)(labels + (size_t)n*CCLS + cc);
        v.x = lb.x*sc; v.y = lb.y*sc; v.z = lb.z*sc; v.w = lb.w*sc;
      } else {
        int b = n - NSUP;
        float base = w_c[b] * sc;
        int p = pred[b];
        v.x = (p == cc+0) ? base : 0.f;
        v.y = (p == cc+1) ? base : 0.f;
        v.z = (p == cc+2) ? base : 0.f;
        v.w = (p == cc+3) ? base : 0.f;
      }
      *(float4*)&sl[r*68 + cc] = v;
    }
    __syncthreads();
    #pragma unroll 4
    for (int kk = 0; kk < 64; ++kk){
      float4 a = *(float4*)&ssx[kk*68 + 4*dg];
      float4 b = *(float4*)&sl[kk*68 + 4*cg];
      float av[4] = {a.x,a.y,a.z,a.w};
      float bv[4] = {b.x,b.y,b.z,b.w};
      #pragma unroll
      for (int i=0;i<4;++i){
        #pragma unroll
        for (int j=0;j<4;++j) acc[i][j] = fmaf(av[i], bv[j], acc[i][j]);
      }
    }
  }
  #pragma unroll
  for (int i=0;i<4;++i){
    #pragma unroll
    for (int j=0;j<4;++j)
      atomicAdd(&protos_un[(size_t)(d0 + 4*dg + i)*CCLS + 4*cg + j], acc[i][j]);
  }
}

// ---------------- 10. protos normalize (cols over D) -> [C][D] ----------------
__global__ __launch_bounds__(256)
void k_protos_norm(const float* __restrict__ protos_un, const float* __restrict__ colsum,
                   float* __restrict__ protos_t){
  int c = blockIdx.x, t = threadIdx.x;
  __shared__ float sh4[4];
  float cs = fmaxf(colsum[c], FEPS);
  float v[4];
  float ss = 0.f;
  #pragma unroll
  for (int i=0;i<4;++i){
    int d = t + 256*i;
    v[i] = protos_un[(size_t)d*CCLS + c] / cs;
    ss += v[i]*v[i];
  }
  ss = blockSum256(ss, sh4);
  float inv = 1.0f / fmaxf(sqrtf(ss), FEPS);
  #pragma unroll
  for (int i=0;i<4;++i){
    int d = t + 256*i;
    protos_t[(size_t)c*DDIM + d] = v[i]*inv;
  }
}

// ---------------- 11. loss2: prototype CE on certain rows ----------------
__global__ __launch_bounds__(256)
void k_loss2(const float* __restrict__ feats, const float* __restrict__ protos_t,
             const int* __restrict__ pred, const float* __restrict__ w_c,
             const float* __restrict__ fnorm, float* __restrict__ scal){
  int row = blockIdx.x, t = threadIdx.x;
  float wc = w_c[row];
  if (wc == 0.f) return;
  __shared__ __align__(16) float f[DDIM];
  __shared__ float z[CCLS];
  float inv = 1.0f / fmaxf(fnorm[row], FEPS);
  { float4 v = ((const float4*)(feats + (size_t)row*DDIM))[t];
    v.x*=inv; v.y*=inv; v.z*=inv; v.w*=inv;
    ((float4*)f)[t] = v; }
  __syncthreads();
  int w = t >> 6, lane = t & 63;
  for (int ci=0; ci<16; ++ci){
    int c = w*16+ci;
    const float4* pc = (const float4*)(protos_t + (size_t)c*DDIM);
    float d = 0.f;
    #pragma unroll
    for (int j=0;j<4;++j){
      float4 a = pc[lane + 64*j];
      float4 b = ((float4*)f)[lane + 64*j];
      d += a.x*b.x+a.y*b.y+a.z*b.z+a.w*b.w;
    }
    d = waveSum(d);
    if (lane==0) z[c] = d;
  }
  __syncthreads();
  if (w == 0){
    float zz = z[lane];
    float m = waveMax(zz);
    float sv = waveSum(expf(zz - m));
    if (lane == 0){
      float lse = m + logf(sv);
      float ce = lse - z[pred[row]];
      atomicAdd(&scal[SC_L2NUM], ce * wc);
    }
  }
}

// ---------------- 12. sim via f16x3 MFMA, transposed (M=supports, N=b-rows),
//                     fused per-chunk top-5 ----------------
__global__ __launch_bounds__(256)
void k_sim_mfma(const float* __restrict__ feats, const float* __restrict__ sup,
                const float* __restrict__ rb, const float* __restrict__ snm,
                float* __restrict__ cval, int* __restrict__ cidx){
  __shared__ __align__(16) _Float16 lds[4*128*LP];   // Ah|Al|Bh|Bl = 40KB
  _Float16* Ah = lds;
  _Float16* Al = lds + 128*LP;
  _Float16* Bh = lds + 2*128*LP;
  _Float16* Bl = lds + 3*128*LP;
  int t = threadIdx.x;
  int m0 = blockIdx.x * 128;           // support chunk base (0..12160)
  int n0 = blockIdx.y * 128;           // batch-row block base
  int w = t >> 6, lane = t & 63;
  int wr = w >> 1, wc = w & 1;
  int lr = lane & 15, lg = lane >> 4;
  int ar = t >> 3, akq = (t & 7);
  const float* Abase = (blockIdx.x < 64) ? (sup + (size_t)m0*DDIM)
                                         : (feats + (size_t)(m0 - NSUP)*DDIM);
  const float* Bbase = feats + (size_t)n0*DDIM;
  f32x4 acc[4][4];
  #pragma unroll
  for (int i=0;i<4;++i){
    #pragma unroll
    for (int j=0;j<4;++j) acc[i][j] = (f32x4)(0.f);
  }
  for (int k0 = 0; k0 < DDIM; k0 += 32){
    float4 av[4], bv[4];
    #pragma unroll
    for (int i=0;i<4;++i){
      av[i] = *(const float4*)(Abase + (size_t)(ar + 32*i)*DDIM + k0 + akq*4);
      bv[i] = *(const float4*)(Bbase + (size_t)(ar + 32*i)*DDIM + k0 + akq*4);
    }
    __syncthreads();
    #pragma unroll
    for (int i=0;i<4;++i){
      half4_t h, l;
      split4(av[i], &h, &l);
      *(half4_t*)&Ah[(ar + 32*i)*LP + akq*4] = h;
      *(half4_t*)&Al[(ar + 32*i)*LP + akq*4] = l;
      split4(bv[i], &h, &l);
      *(half4_t*)&Bh[(ar + 32*i)*LP + akq*4] = h;
      *(half4_t*)&Bl[(ar + 32*i)*LP + akq*4] = l;
    }
    __syncthreads();
    half8_t ah[4], al[4], bh[4], bl[4];
    #pragma unroll
    for (int mi=0;mi<4;++mi){
      const _Float16* p = &Ah[(wr*64 + mi*16 + lr)*LP + lg*8];
      ah[mi] = *(const half8_t*)p;
      al[mi] = *(const half8_t*)(p + 128*LP);
    }
    #pragma unroll
    for (int ni=0;ni<4;++ni){
      const _Float16* p = &Bh[(wc*64 + ni*16 + lr)*LP + lg*8];
      bh[ni] = *(const half8_t*)p;
      bl[ni] = *(const half8_t*)(p + 128*LP);
    }
    #pragma unroll
    for (int mi=0;mi<4;++mi){
      #pragma unroll
      for (int ni=0;ni<4;++ni){
        acc[mi][ni] = __builtin_amdgcn_mfma_f32_16x16x32_f16(ah[mi], bh[ni], acc[mi][ni], 0,0,0);
        acc[mi][ni] = __builtin_amdgcn_mfma_f32_16x16x32_f16(ah[mi], bl[ni], acc[mi][ni], 0,0,0);
        acc[mi][ni] = __builtin_amdgcn_mfma_f32_16x16x32_f16(al[mi], bh[ni], acc[mi][ni], 0,0,0);
      }
    }
  }
  // ---- epilogue: scale, mask, per-thread top5 per b-col, merge ----
  float snv[16];
  #pragma unroll
  for (int mi=0;mi<4;++mi){
    #pragma unroll
    for (int r=0;r<4;++r)
      snv[mi*4+r] = snm[m0 + wr*64 + mi*16 + lg*4 + r];
  }
  float tv[4][5]; int ti[4][5];
  #pragma unroll
  for (int ni=0;ni<4;++ni){
    #pragma unroll
    for (int k=0;k<5;++k){ tv[ni][k] = -INFINITY; ti[ni][k] = 0x7fffffff; }
  }
  #pragma unroll
  for (int ni=0;ni<4;++ni){
    float rbv = rb[n0 + wc*64 + ni*16 + lr];
    #pragma unroll
    for (int mi=0;mi<4;++mi){
      #pragma unroll
      for (int r=0;r<4;++r){
        float sn = snv[mi*4+r];
        float v = acc[mi][ni][r] * rbv * fabsf(sn);
        v = (sn > 0.f) ? v : -INFINITY;
        top5_insert(tv[ni], ti[ni], v, m0 + wr*64 + mi*16 + lg*4 + r);
      }
    }
  }
  // merge across 4 lane-groups (lanes sharing lr = same b-col)
  #pragma unroll
  for (int off = 16; off <= 32; off <<= 1){
    #pragma unroll
    for (int ni=0;ni<4;++ni){
      float pv[5]; int pi[5];
      #pragma unroll
      for (int k=0;k<5;++k){ pv[k] = __shfl_xor(tv[ni][k], off); pi[k] = __shfl_xor(ti[ni][k], off); }
      #pragma unroll
      for (int k=0;k<5;++k) top5_insert(tv[ni], ti[ni], pv[k], pi[k]);
    }
  }
  // cross-wave (wr) merge via LDS
  __syncthreads();
  float* MV = (float*)lds;                 // [128 cols][2 wr][5]
  int*   MI = (int*)(lds + 128*LP);
  if (lg == 0){
    #pragma unroll
    for (int ni=0;ni<4;++ni){
      int col = wc*64 + ni*16 + lr;
      #pragma unroll
      for (int k=0;k<5;++k){
        MV[(col*2 + wr)*5 + k] = tv[ni][k];
        MI[(col*2 + wr)*5 + k] = ti[ni][k];
      }
    }
  }
  __syncthreads();
  if (t < 128){
    float bv[5]; int bi[5];
    #pragma unroll
    for (int k=0;k<5;++k){ bv[k] = MV[(t*2+0)*5 + k]; bi[k] = MI[(t*2+0)*5 + k]; }
    #pragma unroll
    for (int k=0;k<5;++k) top5_insert(bv, bi, MV[(t*2+1)*5 + k], MI[(t*2+1)*5 + k]);
    float* co = cval + (size_t)(n0 + t)*KCAND + blockIdx.x*5;
    int*   ci = cidx + (size_t)(n0 + t)*KCAND + blockIdx.x*5;
    #pragma unroll
    for (int k=0;k<5;++k){ co[k] = bv[k]; ci[k] = bi[k]; }
  }
}

// ---------------- 13. cross-chunk merge + NCL (1 wave per row) ----------------
__global__ __launch_bounds__(256)
void k_merge_ncl(const float* __restrict__ cval, const int* __restrict__ cidx,
                 const float* __restrict__ scores_old, const float* __restrict__ probs,
                 const float* __restrict__ logp, const float* __restrict__ w_c,
                 float* __restrict__ scal){
  int t = threadIdx.x, w = t >> 6, lane = t & 63;
  int b = blockIdx.x*4 + w;
  float bv[5]; int bi[5];
  #pragma unroll
  for (int k=0;k<5;++k){ bv[k] = -INFINITY; bi[k] = 0x7fffffff; }
  #pragma unroll
  for (int it = 0; it < 8; ++it){
    int j = lane + 64*it;
    if (j < KCAND)
      top5_insert(bv, bi, cval[(size_t)b*KCAND + j], cidx[(size_t)b*KCAND + j]);
  }
  #pragma unroll
  for (int off = 32; off > 0; off >>= 1){
    float pv[5]; int pi[5];
    #pragma unroll
    for (int k=0;k<5;++k){ pv[k] = __shfl_xor(bv[k], off); pi[k] = __shfl_xor(bi[k], off); }
    #pragma unroll
    for (int k=0;k<5;++k) top5_insert(bv, bi, pv[k], pi[k]);
  }
  float tg = 0.f;
  #pragma unroll
  for (int k=0;k<5;++k){
    int ix = bi[k];
    const float* srow = (ix < NSUP) ? (scores_old + (size_t)ix*CCLS)
                                    : (probs + (size_t)(ix-NSUP)*CCLS);
    tg += srow[lane];
  }
  tg *= 0.2f;
  float d = tg * logp[(size_t)b*CCLS + lane];
  d = waveSum(d);
  if (lane == 0) atomicAdd(&scal[SC_L3NUM], -d * (1.0f - w_c[b]));
}

// ---------------- 14. final combine ----------------
__global__ void k_final(const float* __restrict__ pm_acc, const float* __restrict__ scal,
                        float* __restrict__ out){
  int lane = threadIdx.x;  // 64 threads
  float pm = pm_acc[lane] * (1.0f/BBATCH);
  float dterm = pm * logf(pm + FEPS);
  float dv = waveSum(dterm);
  if (lane == 0){
    float div = -dv;
    float tsallis = scal[SC_TSAL] * (1.0f/BBATCH);
    float swc = scal[SC_SUMWC];
    float l1 = tsallis - div;
    float l2 = scal[SC_L2NUM] / fmaxf(swc, 1.0f);
    float l3 = scal[SC_L3NUM] / fmaxf((float)BBATCH - swc, 1.0f);
    out[0] = l1 + l2 + l3;
  }
}

// ---------------- launch ----------------
extern "C" void kernel_launch(void* const* d_in, const int* in_sizes, int n_in,
                              void* d_out, int out_size, void* d_ws, size_t ws_size,
                              hipStream_t stream){
  (void)in_sizes; (void)n_in; (void)out_size; (void)ws_size;
  const float* x      = (const float*)d_in[0];
  // d_in[1] = y (unused by the reference loss)
  const float* Wf     = (const float*)d_in[2];
  const float* Wc     = (const float*)d_in[3];
  const float* bc     = (const float*)d_in[4];
  const float* sup    = (const float*)d_in[5];
  const float* labels = (const float*)d_in[6];
  const float* scores = (const float*)d_in[7];
  float* ws = (float*)d_ws;

  float* feats  = ws + OFF_FEATS;     // featp0 / final feats
  float* featp1 = ws + OFF_FEATP1;
  unsigned short* wfth = (unsigned short*)(ws + OFF_WFTH);
  unsigned short* wftl = (unsigned short*)(ws + OFF_WFTL);
  float* probs  = ws + OFF_PROBS;
  float* logp   = ws + OFF_LOGP;
  float* fnorm  = ws + OFF_FNORM;
  float* snorm  = ws + OFF_SNORM;
  float* pmax   = ws + OFF_PMAX;
  float* e_row  = ws + OFF_EROW;
  float* w_c    = ws + OFF_WC;
  int*   pred   = (int*)(ws + OFF_PRED);
  float* rb     = ws + OFF_RB;
  float* snm    = ws + OFF_SNM;
  float* protot = ws + OFF_PROTOT;
  float* cvalp  = ws + OFF_CVAL;
  int*   cidxp  = (int*)(ws + OFF_CIDX);
  float* m_acc  = ws + OFF_MACC;
  float* pm_acc = ws + OFF_PMACC;
  float* colsum = ws + OFF_COLS;
  float* scal   = ws + OFF_SCAL;
  float* protun = ws + OFF_PROTUN;

  hipMemsetAsync(ws + OFF_ZERO, 0, (WS_END - OFF_ZERO)*sizeof(float), stream);

  k_entropy      <<<BBATCH, 256, 0, stream>>>(x, e_row, scal);
  k_wft          <<<dim3(DDIM/64, LLEN/64), 256, 0, stream>>>(Wf, wfth, wftl);
  k_feats_mfma   <<<dim3(DDIM/128, BBATCH/128, 2), 256, 0, stream>>>(x, wfth, wftl, feats);
  k_supnorm      <<<NSUP/4, 256, 0, stream>>>(sup, snorm);
  k_logits       <<<BBATCH, 256, 0, stream>>>(feats, featp1, Wc, bc, probs, logp, pmax, pred, fnorm, scal);
  k_mask         <<<32, 256, 0, stream>>>(e_row, pmax, fnorm, snorm, pred, w_c, rb, snm, colsum, scal);
  k_colsum_labels<<<32, 256, 0, stream>>>(labels, colsum);
  k_m_accum      <<<64, 256, 0, stream>>>(probs, w_c, m_acc);
  k_loss1        <<<64, 256, 0, stream>>>(probs, m_acc, pm_acc, scal);
  k_protos_gemm  <<<dim3(16, 8), 256, 0, stream>>>(sup, feats, labels, pred, w_c, snm, protun);
  k_protos_norm  <<<CCLS, 256, 0, stream>>>(protun, colsum, protot);
  k_loss2        <<<BBATCH, 256, 0, stream>>>(feats, protot, pred, w_c, fnorm, scal);
  k_sim_mfma     <<<dim3(KCHUNK, BBATCH/128), 256, 0, stream>>>(feats, sup, rb, snm, cvalp, cidxp);
  k_merge_ncl    <<<BBATCH/4, 256, 0, stream>>>(cvalp, cidxp, scores, probs, logp, w_c, scal);
  k_final        <<<1, 64, 0, stream>>>(pm_acc, scal, (float*)d_out);
}